// Round 4
// baseline (250.111 us; speedup 1.0000x reference)
//
#include <hip/hip_runtime.h>

// LearnedQueryAttention: B=8, L=4096, KD=512, ED=1024, H=8. All I/O fp32.
// Raw-reshape semantics: head h owns the contiguous flat slab
// f = h*(L+1)*(C/H) + row*(C/H) + d of per-batch [X_flat | bias]; only
// f >= L*C touches the bias token (head 7, rows 4089..4096). Row-aligned
// pointer select is exact for both K (64 f/row) and V (128 f/row).
//
// Round notes (this revision):
//  - R3 post-mortem: compiler UNDID source-level batching (VGPR_Count=32,
//    cannot hold even 2 of 24 floatx4 results) -> MLP~1 persisted, 78us.
//    This round makes MLP structural:
//    * ALL loads of the block (K, w, b, AND V -- V never depended on
//      scores) issued up front, then __builtin_amdgcn_sched_barrier(0):
//      scheduler cannot sink loads past it; regalloc must keep them live.
//    * 64-row blocks (grid 64x64): 4K+8V+8 scalar loads/wave ~= 80 VGPR,
//      fits __launch_bounds__(256,4) cap of 128 without spills; ~2.7
//      rounds of block churn per CU.
//    * Verification signal: VGPR_Count must jump to ~80-110.
//  - m=0 softmax frame retained (|scores|<~1): no max pass, partials sum
//    directly. Row 4096 handled analytically in kernel 2.
#define BATCH 8
#define LSEQ  4096
#define LP    4097
#define KDIM  512
#define EDIM  1024
#define NH    8
#define DK    64
#define DV    128
#define NG    64          // B*H groups
#define NCH   64          // chunks per group (64 rows each)
#define LN_EPS 1e-5f

typedef float floatx4 __attribute__((ext_vector_type(4)));

// ---------------------------------------------------------------------------
// Kernel 1: per (group g, chunk cg of 64 rows); each of 4 waves owns 16 rows
// end-to-end in registers. All 20 loads issued before any compute
// (sched_barrier-fenced). One barrier (cross-wave partial merge).
// Grid (64, 64), 256 threads.
// ---------------------------------------------------------------------------
__global__ __launch_bounds__(256, 4) void lqa_fused_kernel(
    const float* __restrict__ keys, const float* __restrict__ k_bias,
    const float* __restrict__ values, const float* __restrict__ v_bias,
    const float* __restrict__ query, const float* __restrict__ sw,
    const float* __restrict__ sb, float* __restrict__ partials,
    float* __restrict__ zstats)
{
    const int cg = blockIdx.x;               // 0..63
    const int g  = blockIdx.y;               // 0..63
    const int b = g >> 3, h = g & 7;
    const int t = threadIdx.x;
    const int w = t >> 6;                    // wave 0..3
    const int lane = t & 63;
    const int row0 = cg * 64 + w * 16;       // this wave's 16 rows

    __shared__ float red[4 * DV];
    __shared__ float zred[4];

    const int gid = lane >> 4, l16 = lane & 15;     // Phase-A lane mapping
    const int hi = (lane >> 5) & 1;                  // Phase-B lane mapping
    const int d0 = (lane & 31) * 4;

    const float* kp = keys + (long long)b * (LSEQ * KDIM);
    const float* vp = values + (long long)b * (LSEQ * EDIM);
    const int fheadk = h * (LP * DK);
    const int fheadv = h * (LP * DV);
    const float* wptr = sw + h * LP;
    const float* bptr = sb + h * LP;

    // ================= load cluster: issue EVERYTHING =================
    const floatx4 q = *reinterpret_cast<const floatx4*>(query + h * DK + l16 * 4);
    floatx4 kv[4];
    float wv[4], bv[4];
#pragma unroll
    for (int j = 0; j < 4; ++j) {
        const int row = row0 + 4 * j + gid;
        const int f = fheadk + row * DK;                // row-aligned select
        const float* rowp = (f < LSEQ * KDIM) ? (kp + f)
                                              : (k_bias + (f - LSEQ * KDIM));
        kv[j] = *reinterpret_cast<const floatx4*>(rowp + l16 * 4);
        wv[j] = wptr[row];
        bv[j] = bptr[row];
    }
    floatx4 v0[4], v1[4];
#pragma unroll
    for (int j = 0; j < 4; ++j) {
        const int fA = fheadv + (row0 + 4 * j + hi) * DV;
        const float* rpA = (fA < LSEQ * EDIM) ? (vp + fA)
                                              : (v_bias + (fA - LSEQ * EDIM));
        v0[j] = *reinterpret_cast<const floatx4*>(rpA + d0);
        const int fB = fheadv + (row0 + 4 * j + 2 + hi) * DV;
        const float* rpB = (fB < LSEQ * EDIM) ? (vp + fB)
                                              : (v_bias + (fB - LSEQ * EDIM));
        v1[j] = *reinterpret_cast<const floatx4*>(rpB + d0);
    }
    __builtin_amdgcn_sched_barrier(0);   // loads stay above; compute below

    // ================= compute (runs under V-load latency) =================
    float s[4];
#pragma unroll
    for (int j = 0; j < 4; ++j)
        s[j] = q.x * kv[j].x + q.y * kv[j].y + q.z * kv[j].z + q.w * kv[j].w;
#pragma unroll
    for (int j = 0; j < 4; ++j) s[j] += __shfl_xor(s[j], 1);
#pragma unroll
    for (int j = 0; j < 4; ++j) s[j] += __shfl_xor(s[j], 2);
#pragma unroll
    for (int j = 0; j < 4; ++j) s[j] += __shfl_xor(s[j], 4);
#pragma unroll
    for (int j = 0; j < 4; ++j) s[j] += __shfl_xor(s[j], 8);
    float e[4];
    float z = 0.f;
#pragma unroll
    for (int j = 0; j < 4; ++j) {
        e[j] = __expf(s[j] * wv[j] + bv[j]);            // m=0 frame
        z += e[j];
    }
    z += __shfl_xor(z, 16);
    z += __shfl_xor(z, 32);

    // broadcasts: e of rows (4j+hi) and (4j+2+hi)
    float e0[4], e1[4];
#pragma unroll
    for (int j = 0; j < 4; ++j) e0[j] = __shfl(e[j], 16 * hi, 64);
#pragma unroll
    for (int j = 0; j < 4; ++j) e1[j] = __shfl(e[j], 16 * (2 + hi), 64);

    float a0 = 0.f, a1 = 0.f, a2 = 0.f, a3 = 0.f;
#pragma unroll
    for (int j = 0; j < 4; ++j) {
        a0 += e0[j] * v0[j].x; a1 += e0[j] * v0[j].y;
        a2 += e0[j] * v0[j].z; a3 += e0[j] * v0[j].w;
        a0 += e1[j] * v1[j].x; a1 += e1[j] * v1[j].y;
        a2 += e1[j] * v1[j].z; a3 += e1[j] * v1[j].w;
    }
    a0 += __shfl_xor(a0, 32);
    a1 += __shfl_xor(a1, 32);
    a2 += __shfl_xor(a2, 32);
    a3 += __shfl_xor(a3, 32);

    // ---- tail: merge the 4 waves' partials (single barrier) ----
    if (lane < 32) {
        float* dst = red + w * DV + d0;
        dst[0] = a0; dst[1] = a1; dst[2] = a2; dst[3] = a3;
    }
    if (lane == 0) zred[w] = z;
    __syncthreads();
    if (t < DV) {
        const float sum = red[t] + red[DV + t] + red[2 * DV + t] + red[3 * DV + t];
        partials[((long long)(g * NCH + cg)) * DV + t] = sum;
    } else if (t == DV) {
        zstats[g * NCH + cg] = zred[0] + zred[1] + zred[2] + zred[3];
    }
}

// ---------------------------------------------------------------------------
// Kernel 2: combine (m=0 frame: plain sums) + row-4096 token + LayerNorm.
// One block per batch, 1024 threads (one per embed dim). NC=64 version.
// ---------------------------------------------------------------------------
__global__ __launch_bounds__(1024) void lqa_combine_ln_kernel(
    const float* __restrict__ partials, const float* __restrict__ zstats,
    const float* __restrict__ keys, const float* __restrict__ values,
    const float* __restrict__ k_bias, const float* __restrict__ v_bias,
    const float* __restrict__ query, const float* __restrict__ sw,
    const float* __restrict__ sb, const float* __restrict__ gamma,
    const float* __restrict__ beta, float* __restrict__ out)
{
    const int b = blockIdx.x;
    const int t = threadIdx.x;
    __shared__ float zh[NH];                 // per-head Z (finally incl. e_bias)
    __shared__ float eb[NH];                 // row-4096 exp weight per head
    __shared__ float r1[16], r2[16];

    // S1 (waves 0-7): Z = sum_c z_c; one wave per head, 64 chunks/wave
    if (t < 512) {
        float zv = zstats[(b * NH + (t >> 6)) * NCH + (t & 63)];
        zv += __shfl_xor(zv, 1);
        zv += __shfl_xor(zv, 2);
        zv += __shfl_xor(zv, 4);
        zv += __shfl_xor(zv, 8);
        zv += __shfl_xor(zv, 16);
        zv += __shfl_xor(zv, 32);
        if ((t & 63) == 0) zh[t >> 6] = zv;
    } else if (t < 640) {
        // S2 (waves 8-9): row-4096 score per head: 16-lane dot + exp
        const int tt = t - 512;
        const int h = tt >> 4, l16 = tt & 15;
        const floatx4 q = *reinterpret_cast<const floatx4*>(query + h * DK + l16 * 4);
        const int fk = h * (LP * DK) + LSEQ * DK;       // flat row 4096
        const float* kr = (fk < LSEQ * KDIM)
            ? keys + (long long)b * (LSEQ * KDIM) + fk
            : k_bias + (fk - LSEQ * KDIM);
        const floatx4 k = *reinterpret_cast<const floatx4*>(kr + l16 * 4);
        float s = q.x * k.x + q.y * k.y + q.z * k.z + q.w * k.w;
        s += __shfl_xor(s, 1);
        s += __shfl_xor(s, 2);
        s += __shfl_xor(s, 4);
        s += __shfl_xor(s, 8);
        if (l16 == 0) eb[h] = __expf(s * sw[h * LP + LSEQ] + sb[h * LP + LSEQ]);
    }
    __syncthreads();
    if (t < NH) zh[t] += eb[t];
    __syncthreads();

    // S3: each thread owns one embed dim e = t = h*128 + d
    const int h = t >> 7, d = t & 127;
    const float* src = partials + ((long long)((b * NH + h) * NCH)) * DV + d;
    float sum = 0.f;
#pragma unroll
    for (int c = 0; c < NCH; ++c) sum += src[c * DV];
    const int fv = h * (LP * DV) + LSEQ * DV + d;       // flat row 4096
    const float v4 = (fv < LSEQ * EDIM)
        ? values[(long long)b * (LSEQ * EDIM) + fv]
        : v_bias[fv - LSEQ * EDIM];
    const float av = (sum + eb[h] * v4) / zh[h];

    // S4: LayerNorm over 1024 dims: wave shuffle reduce + 16-wave LDS combine
    float s1 = av, s2 = av * av;
    s1 += __shfl_xor(s1, 1);  s2 += __shfl_xor(s2, 1);
    s1 += __shfl_xor(s1, 2);  s2 += __shfl_xor(s2, 2);
    s1 += __shfl_xor(s1, 4);  s2 += __shfl_xor(s2, 4);
    s1 += __shfl_xor(s1, 8);  s2 += __shfl_xor(s2, 8);
    s1 += __shfl_xor(s1, 16); s2 += __shfl_xor(s2, 16);
    s1 += __shfl_xor(s1, 32); s2 += __shfl_xor(s2, 32);
    if ((t & 63) == 0) { r1[t >> 6] = s1; r2[t >> 6] = s2; }
    __syncthreads();
    float fs1 = 0.f, fs2 = 0.f;
#pragma unroll
    for (int i = 0; i < 16; ++i) { fs1 += r1[i]; fs2 += r2[i]; }
    const float mean = fs1 * (1.0f / EDIM);
    const float var = fs2 * (1.0f / EDIM) - mean * mean;
    const float inv = rsqrtf(var + LN_EPS);
    out[(long long)b * EDIM + t] = (av - mean) * inv * gamma[t] + beta[t];
}

// ---------------------------------------------------------------------------
extern "C" void kernel_launch(void* const* d_in, const int* in_sizes, int n_in,
                              void* d_out, int out_size, void* d_ws, size_t ws_size,
                              hipStream_t stream) {
    const float* keys   = (const float*)d_in[0];
    const float* values = (const float*)d_in[1];
    const float* query  = (const float*)d_in[2];
    const float* k_bias = (const float*)d_in[3];
    const float* v_bias = (const float*)d_in[4];
    const float* sw     = (const float*)d_in[5];
    const float* sb     = (const float*)d_in[6];
    const float* gamma  = (const float*)d_in[7];
    const float* beta   = (const float*)d_in[8];
    float* out = (float*)d_out;

    // ws layout (floats): partials[64][64][128] | zstats[64*64] (~2.1 MB)
    float* ws = (float*)d_ws;
    float* partials = ws;
    float* zstats = ws + (long long)NG * NCH * DV;

    lqa_fused_kernel<<<dim3(NCH, NG), 256, 0, stream>>>(
        keys, k_bias, values, v_bias, query, sw, sb, partials, zstats);
    lqa_combine_ln_kernel<<<BATCH, 1024, 0, stream>>>(
        partials, zstats, keys, values, k_bias, v_bias, query, sw, sb,
        gamma, beta, out);
}